// Round 1
// baseline (2418.961 us; speedup 1.0000x reference)
//
#include <hip/hip_runtime.h>

// Problem dims (fixed per reference)
#define D_DIM 2048
#define I_DIM 1024
#define E_NUM 32
#define TOPK 4
#define T_TOK 4096
#define CAP_R 1024          // per-routed-expert token capacity (mean 512, sigma ~21)
#define ALPHA 7.0f

// GEMM tiling
#define BM 128
#define BN 128
#define BK 32
#define LSTR 40             // LDS row stride in shorts (32 + 8 pad) = 80 B, 16B-aligned

typedef __attribute__((ext_vector_type(8))) short short8;
typedef __attribute__((ext_vector_type(4))) float floatx4;

static __device__ __forceinline__ unsigned short f2bf(float f) {
    union { float f; unsigned u; } v; v.f = f;
    unsigned u = v.u;
    u += 0x7FFFu + ((u >> 16) & 1u);   // RNE
    return (unsigned short)(u >> 16);
}

// ---------------------------------------------------------------------------
// Router: logits -> sqrt(softplus) -> top-4 by (score+bias) -> renorm weights
// scatter (token, weight) into per-expert lists.
// ---------------------------------------------------------------------------
__global__ __launch_bounds__(256) void router_kernel(
    const float* __restrict__ x, const float* __restrict__ rw,
    const float* __restrict__ bias,
    int* __restrict__ counts, int* __restrict__ tlist, float* __restrict__ twgt)
{
    const int t = blockIdx.x;
    const int tid = threadIdx.x;
    const int wave = tid >> 6, lane = tid & 63;
    __shared__ float xs[D_DIM];
    __shared__ float logits[E_NUM];
    const float* xr = x + (long)t * D_DIM;
    for (int i = tid; i < D_DIM; i += 256) xs[i] = xr[i];
    __syncthreads();
    for (int e = wave; e < E_NUM; e += 4) {
        const float* wr = rw + (long)e * D_DIM;
        float acc = 0.f;
        for (int i = lane; i < D_DIM; i += 64) acc += xs[i] * wr[i];
        for (int off = 32; off > 0; off >>= 1) acc += __shfl_down(acc, off);
        if (lane == 0) logits[e] = acc;
    }
    __syncthreads();
    if (tid == 0) {
        float sc[E_NUM], bsc[E_NUM];
        for (int e2 = 0; e2 < E_NUM; ++e2) {
            float l = logits[e2];
            float sp = (l > 20.f) ? l : log1pf(expf(l));
            float s = sqrtf(sp);
            sc[e2] = s;
            bsc[e2] = s + bias[e2];
        }
        int sel[TOPK]; float ssum = 0.f;
        unsigned usedmask = 0;
        for (int k = 0; k < TOPK; ++k) {
            int best = 0; float bv = -1e30f;
            for (int e2 = 0; e2 < E_NUM; ++e2)
                if (!((usedmask >> e2) & 1u) && bsc[e2] > bv) { bv = bsc[e2]; best = e2; }
            usedmask |= 1u << best;
            sel[k] = best;
            ssum += sc[best];
        }
        float inv = 1.f / (ssum + 1e-20f);
        for (int k = 0; k < TOPK; ++k) {
            int e2 = sel[k];
            int pos = atomicAdd(&counts[e2], 1);
            if (pos < CAP_R) {
                tlist[e2 * CAP_R + pos] = t;
                twgt[e2 * CAP_R + pos] = sc[e2] * inv;
            }
        }
    }
}

// ---------------------------------------------------------------------------
// Fused gate+up GEMM per expert (e==32 -> shared expert, identity token list).
// C_g = X_e @ Wg^T, C_u = X_e @ Wu^T ; h = silu(clamp(g)) * clamp(u) -> bf16
// ---------------------------------------------------------------------------
__global__ __launch_bounds__(256, 2) void gateup_kernel(
    const float* __restrict__ x,
    const float* __restrict__ gate_w, const float* __restrict__ up_w,
    const float* __restrict__ sgw, const float* __restrict__ suw,
    const int* __restrict__ counts, const int* __restrict__ tlist,
    unsigned short* __restrict__ hbuf)
{
    const int e = blockIdx.z;
    const int mtile = blockIdx.y;
    const int ntile = blockIdx.x;
    int cnt = (e == E_NUM) ? T_TOK : min(counts[e], CAP_R);
    if (mtile * BM >= cnt) return;

    const float* gw; const float* uw; const int* lst = nullptr; long hbase;
    if (e < E_NUM) {
        gw = gate_w + (long)e * I_DIM * D_DIM;
        uw = up_w   + (long)e * I_DIM * D_DIM;
        lst = tlist + e * CAP_R;
        hbase = (long)e * CAP_R;
    } else {
        gw = sgw; uw = suw; hbase = (long)E_NUM * CAP_R;
    }

    __shared__ __align__(16) short As[BM * LSTR];
    __shared__ __align__(16) short Bg[BN * LSTR];
    __shared__ __align__(16) short Bu[BN * LSTR];

    const int tid = threadIdx.x;
    const int srow = tid >> 3;          // 0..31
    const int scol = (tid & 7) << 2;    // 0,4,...,28

    const float* aptr[4];
    for (int i = 0; i < 4; ++i) {
        int r = mtile * BM + srow + i * 32;
        int rr = (r < cnt) ? r : (cnt - 1);           // clamp; masked at store
        int tok = (e < E_NUM) ? lst[rr] : rr;
        aptr[i] = x + (long)tok * D_DIM + scol;
    }
    const float* gptr[4]; const float* uptr[4];
    for (int i = 0; i < 4; ++i) {
        long n = ntile * BN + srow + i * 32;
        gptr[i] = gw + n * D_DIM + scol;
        uptr[i] = uw + n * D_DIM + scol;
    }

    floatx4 accg[4][4] = {};
    floatx4 accu[4][4] = {};

    const int wave = tid >> 6, lane = tid & 63;
    const int wm = wave >> 1, wn = wave & 1;
    const int quad = lane >> 4, l16 = lane & 15;

    for (int k0 = 0; k0 < D_DIM; k0 += BK) {
        for (int i = 0; i < 4; ++i) {
            float4 va = *(const float4*)(aptr[i] + k0);
            float4 vg = *(const float4*)(gptr[i] + k0);
            float4 vu = *(const float4*)(uptr[i] + k0);
            int r = srow + i * 32;
            unsigned* pa = (unsigned*)&As[r * LSTR + scol];
            pa[0] = f2bf(va.x) | ((unsigned)f2bf(va.y) << 16);
            pa[1] = f2bf(va.z) | ((unsigned)f2bf(va.w) << 16);
            unsigned* pg = (unsigned*)&Bg[r * LSTR + scol];
            pg[0] = f2bf(vg.x) | ((unsigned)f2bf(vg.y) << 16);
            pg[1] = f2bf(vg.z) | ((unsigned)f2bf(vg.w) << 16);
            unsigned* pu = (unsigned*)&Bu[r * LSTR + scol];
            pu[0] = f2bf(vu.x) | ((unsigned)f2bf(vu.y) << 16);
            pu[1] = f2bf(vu.z) | ((unsigned)f2bf(vu.w) << 16);
        }
        __syncthreads();
        short8 af[4];
        for (int mi = 0; mi < 4; ++mi)
            af[mi] = *(const short8*)&As[(wm * 64 + mi * 16 + l16) * LSTR + quad * 8];
        for (int ni = 0; ni < 4; ++ni) {
            short8 bg = *(const short8*)&Bg[(wn * 64 + ni * 16 + l16) * LSTR + quad * 8];
            short8 bu = *(const short8*)&Bu[(wn * 64 + ni * 16 + l16) * LSTR + quad * 8];
            for (int mi = 0; mi < 4; ++mi) {
                accg[mi][ni] = __builtin_amdgcn_mfma_f32_16x16x32_bf16(af[mi], bg, accg[mi][ni], 0, 0, 0);
                accu[mi][ni] = __builtin_amdgcn_mfma_f32_16x16x32_bf16(af[mi], bu, accu[mi][ni], 0, 0, 0);
            }
        }
        __syncthreads();
    }

    // epilogue: clamp, silu(g)*u, bf16 store to h scratch
    for (int mi = 0; mi < 4; ++mi)
    for (int r4 = 0; r4 < 4; ++r4) {
        int lrow = wm * 64 + mi * 16 + quad * 4 + r4;
        int grow = mtile * BM + lrow;
        if (grow >= cnt) continue;
        unsigned short* hrow = hbuf + (hbase + grow) * I_DIM + ntile * BN + wn * 64 + l16;
        for (int ni = 0; ni < 4; ++ni) {
            float g = accg[mi][ni][r4];
            float u = accu[mi][ni][r4];
            g = fminf(fmaxf(g, -ALPHA), ALPHA);
            u = fminf(fmaxf(u, -ALPHA), ALPHA);
            float h = g / (1.f + expf(-g)) * u;
            hrow[ni * 16] = f2bf(h);
        }
    }
}

// ---------------------------------------------------------------------------
// Down GEMM per expert: C = h_e @ Wd^T ; out[token] += p * C  (atomic fp32)
// ---------------------------------------------------------------------------
__global__ __launch_bounds__(256, 2) void down_kernel(
    const unsigned short* __restrict__ hbuf,
    const float* __restrict__ down_w, const float* __restrict__ sdw,
    const int* __restrict__ counts, const int* __restrict__ tlist,
    const float* __restrict__ twgt,
    float* __restrict__ out)
{
    const int e = blockIdx.z;
    const int mtile = blockIdx.y;
    const int ntile = blockIdx.x;      // D/128 = 16
    int cnt = (e == E_NUM) ? T_TOK : min(counts[e], CAP_R);
    if (mtile * BM >= cnt) return;

    const float* dw = (e < E_NUM) ? down_w + (long)e * D_DIM * I_DIM : sdw;
    const long hbase = (e < E_NUM) ? (long)e * CAP_R : (long)E_NUM * CAP_R;
    const int* lst = tlist + (e < E_NUM ? e : 0) * CAP_R;
    const float* wgt = twgt + (e < E_NUM ? e : 0) * CAP_R;

    __shared__ __align__(16) short As[BM * LSTR];
    __shared__ __align__(16) short Bs[BN * LSTR];

    const int tid = threadIdx.x;
    // A (bf16 h) staging: 16B per load, 2 loads/thread per K-tile
    const int ar = tid >> 2;           // 0..63
    const int aseg = (tid & 3) << 3;   // shorts: 0,8,16,24
    const unsigned short* ap0 = hbuf + (hbase + mtile * BM + ar) * I_DIM + aseg;
    const unsigned short* ap1 = hbuf + (hbase + mtile * BM + ar + 64) * I_DIM + aseg;
    // B (fp32 down_w) staging
    const int srow = tid >> 3;
    const int scol = (tid & 7) << 2;
    const float* bptr[4];
    for (int i = 0; i < 4; ++i)
        bptr[i] = dw + (long)(ntile * BN + srow + i * 32) * I_DIM + scol;

    floatx4 acc[4][4] = {};
    const int wave = tid >> 6, lane = tid & 63;
    const int wm = wave >> 1, wn = wave & 1;
    const int quad = lane >> 4, l16 = lane & 15;

    for (int k0 = 0; k0 < I_DIM; k0 += BK) {
        *(uint4*)&As[ar * LSTR + aseg] = *(const uint4*)(ap0 + k0);
        *(uint4*)&As[(ar + 64) * LSTR + aseg] = *(const uint4*)(ap1 + k0);
        for (int i = 0; i < 4; ++i) {
            float4 v = *(const float4*)(bptr[i] + k0);
            unsigned* pb = (unsigned*)&Bs[(srow + i * 32) * LSTR + scol];
            pb[0] = f2bf(v.x) | ((unsigned)f2bf(v.y) << 16);
            pb[1] = f2bf(v.z) | ((unsigned)f2bf(v.w) << 16);
        }
        __syncthreads();
        short8 af[4];
        for (int mi = 0; mi < 4; ++mi)
            af[mi] = *(const short8*)&As[(wm * 64 + mi * 16 + l16) * LSTR + quad * 8];
        for (int ni = 0; ni < 4; ++ni) {
            short8 bf = *(const short8*)&Bs[(wn * 64 + ni * 16 + l16) * LSTR + quad * 8];
            for (int mi = 0; mi < 4; ++mi)
                acc[mi][ni] = __builtin_amdgcn_mfma_f32_16x16x32_bf16(af[mi], bf, acc[mi][ni], 0, 0, 0);
        }
        __syncthreads();
    }

    for (int mi = 0; mi < 4; ++mi)
    for (int r4 = 0; r4 < 4; ++r4) {
        int lrow = wm * 64 + mi * 16 + quad * 4 + r4;
        int grow = mtile * BM + lrow;
        if (grow >= cnt) continue;
        int tok; float w;
        if (e < E_NUM) { tok = lst[grow]; w = wgt[grow]; }
        else           { tok = grow;     w = 1.f; }
        float* orow = out + (long)tok * D_DIM + ntile * BN + wn * 64 + l16;
        for (int ni = 0; ni < 4; ++ni)
            atomicAdd(orow + ni * 16, w * acc[mi][ni][r4]);
    }
}

// ---------------------------------------------------------------------------
extern "C" void kernel_launch(void* const* d_in, const int* in_sizes, int n_in,
                              void* d_out, int out_size, void* d_ws, size_t ws_size,
                              hipStream_t stream) {
    const float* hidden   = (const float*)d_in[0];
    const float* router_w = (const float*)d_in[1];
    const float* ebias    = (const float*)d_in[2];
    const float* gate_w   = (const float*)d_in[3];
    const float* up_w     = (const float*)d_in[4];
    const float* down_w   = (const float*)d_in[5];
    const float* sgw      = (const float*)d_in[6];
    const float* suw      = (const float*)d_in[7];
    const float* sdw      = (const float*)d_in[8];
    float* out = (float*)d_out;

    char* ws = (char*)d_ws;
    int*   counts = (int*)ws;                                  // 33 ints (pad 256)
    int*   tlist  = (int*)(ws + 256);                          // 32*1024 ints
    float* twgt   = (float*)(ws + 256 + E_NUM * CAP_R * 4);    // 32*1024 floats
    unsigned short* hbuf = (unsigned short*)(ws + 256 + 2 * E_NUM * CAP_R * 4);
    // hbuf: (32*1024 + 4096) rows * 1024 bf16 = ~75.5 MB

    hipMemsetAsync(counts, 0, 256, stream);
    hipMemsetAsync(out, 0, (size_t)out_size * sizeof(float), stream);

    router_kernel<<<T_TOK, 256, 0, stream>>>(hidden, router_w, ebias, counts, tlist, twgt);
    gateup_kernel<<<dim3(I_DIM / BN, T_TOK / BM, E_NUM + 1), 256, 0, stream>>>(
        hidden, gate_w, up_w, sgw, suw, counts, tlist, hbuf);
    down_kernel<<<dim3(D_DIM / BN, T_TOK / BM, E_NUM + 1), 256, 0, stream>>>(
        hbuf, down_w, sdw, counts, tlist, twgt, out);
}